// Round 6
// baseline (252.035 us; speedup 1.0000x reference)
//
#include <hip/hip_runtime.h>
#include <hip/hip_bf16.h>
#include <math.h>

#define B_    16
#define M_    128
#define T_    2048
#define H_    512
#define TOUT_ 2049

typedef unsigned short u16;
typedef unsigned int   u32;
typedef __bf16 bf16x8 __attribute__((ext_vector_type(8)));
typedef float  f32x16 __attribute__((ext_vector_type(16)));
typedef float  f32x4  __attribute__((ext_vector_type(4)));
typedef u32    u32x4  __attribute__((ext_vector_type(4)));
typedef u32    u32x2  __attribute__((ext_vector_type(2)));

// ws layout (float units):
#define A_OFF     0                       // fp32 Ao only [128][128]
#define C_OFF     16384                   // c[3][128]
#define MEAN_OFF  16896                   // meanv [2048]
#define AQKBF_OFF 19200                   // u16 [256][128] = 16384 fl
#define AOBF_OFF  35584                   // u16 [128][128] = 8192 fl
#define QT_OFF    43776
#define KT_OFF    (43776 + 2097152)
#define VB_OFF    (43776 + 2 * 2097152)

static __device__ __forceinline__ u16 f2bf(float f) {
  u32 u = __float_as_uint(f);
  u = (u + 0x7FFFu + ((u >> 16) & 1u)) >> 16;
  return (u16)u;
}
static __device__ __forceinline__ u32 pk2(float lo, float hi) {
  __hip_bfloat162 h = __float22bfloat162_rn(float2{lo, hi});
  u32 r;
  __builtin_memcpy(&r, &h, 4);
  return r;
}
static __device__ __forceinline__ bf16x8 ldfrag(const u16* p) {
  return __builtin_bit_cast(bf16x8, *(const u32x4*)p);
}
static __device__ __forceinline__ float ex2(float x) {
#if __has_builtin(__builtin_amdgcn_exp2f)
  return __builtin_amdgcn_exp2f(x);  // v_exp_f32 = 2^x
#else
  return exp2f(x);
#endif
}

// ---------------------------------------------------------------------------
__global__ __launch_bounds__(128) void fuse_weights_all(
    const float* __restrict__ W1q, const float* __restrict__ b1q,
    const float* __restrict__ W2q, const float* __restrict__ b2q,
    const float* __restrict__ W1k, const float* __restrict__ b1k,
    const float* __restrict__ W2k, const float* __restrict__ b2k,
    const float* __restrict__ W1o, const float* __restrict__ b1o,
    const float* __restrict__ W2o, const float* __restrict__ b2o,
    float* __restrict__ A, float* __restrict__ c,
    u16* __restrict__ Aqk_bf, u16* __restrict__ Ao_bf) {
  __shared__ float w2row[H_];
  int which = blockIdx.x >> 7;
  int o = blockIdx.x & 127;
  const float* W1 = which == 0 ? W1q : which == 1 ? W1k : W1o;
  const float* b1 = which == 0 ? b1q : which == 1 ? b1k : b1o;
  const float* W2 = which == 0 ? W2q : which == 1 ? W2k : W2o;
  const float* b2 = which == 0 ? b2q : which == 1 ? b2k : b2o;
  int m = threadIdx.x;
  for (int h = m; h < H_; h += 128) w2row[h] = W2[o * H_ + h];
  __syncthreads();
  float acc = 0.f;
#pragma unroll 8
  for (int h = 0; h < H_; ++h) acc = fmaf(w2row[h], W1[h * M_ + m], acc);
  u16 ab = f2bf(acc);
  if (which == 0)      Aqk_bf[o * 128 + m] = ab;
  else if (which == 1) Aqk_bf[(128 + o) * 128 + m] = ab;
  else               { Ao_bf[o * 128 + m] = ab; A[o * M_ + m] = acc; }
  if (m < 64) {
    float cc = 0.f;
    for (int h = m; h < H_; h += 64) cc = fmaf(w2row[h], b1[h], cc);
#pragma unroll
    for (int off = 32; off > 0; off >>= 1) cc += __shfl_down(cc, off, 64);
    if (m == 0) c[which * 128 + o] = cc + b2[o];
  }
}

// ---------------------------------------------------------------------------
// prep: blocks [0,512) = q/k MLP (MFMA, coalesced I/O);
//       blocks [512,2560) = value cast + windowed mean
// q outputs (o<128) pre-scaled by log2(e): exp(exp(qk)) =
// exp2(exp2(qk*log2e + log2(log2e))).
#define XS 68

__global__ __launch_bounds__(256) void prep_kernel(
    const float* __restrict__ pattern, const u16* __restrict__ Aqk_bf,
    const float* __restrict__ cqk, u16* __restrict__ qT, u16* __restrict__ kT,
    const float* __restrict__ value, u16* __restrict__ vb,
    float* __restrict__ meanv) {
  __shared__ alignas(16) float xsf[128 * XS];
  int bx = blockIdx.x;
  int tid = threadIdx.x;

  if (bx >= 512) {
    int bm = bx - 512;
    float* red = xsf;
    const float* row = value + (size_t)bm * T_;
    int i0 = tid * 8;
    float4 a = *(const float4*)(row + i0);
    float4 bq = *(const float4*)(row + i0 + 4);
    u32x4 o = {pk2(a.x, a.y), pk2(a.z, a.w), pk2(bq.x, bq.y), pk2(bq.z, bq.w)};
    *(u32x4*)&vb[(size_t)bm * T_ + i0] = o;
    float vals[8] = {a.x, a.y, a.z, a.w, bq.x, bq.y, bq.z, bq.w};
    float s = 0.f;
#pragma unroll
    for (int j = 0; j < 8; ++j) {
      int idx = i0 + j;
      if (idx >= 33 && idx < T_ - 1) s += vals[j];
    }
    red[tid] = s;
    __syncthreads();
    for (int st = 128; st > 0; st >>= 1) {
      if (tid < st) red[tid] += red[tid + st];
      __syncthreads();
    }
    if (tid == 0) meanv[bm] = red[0] * (1.f / 2014.f);
    return;
  }

  int b = bx >> 5;
  int t0 = (bx & 31) * 64;
  int lane = tid & 63;
  int wv = tid >> 6;
  int l31 = lane & 31;
  int lh8 = (lane >> 5) * 8;

  bf16x8 afr[2][8];
#pragma unroll
  for (int i = 0; i < 2; ++i) {
    const u16* ap = Aqk_bf + ((2 * wv + i) * 32 + l31) * 128 + lh8;
#pragma unroll
    for (int s = 0; s < 8; ++s) afr[i][s] = ldfrag(ap + 16 * s);
  }

#pragma unroll
  for (int rep = 0; rep < 8; ++rep) {
    int m = rep * 16 + (tid >> 4);
    int tc = (tid & 15) * 4;
    float4 v = *(const float4*)&pattern[(size_t)(b * M_ + m) * T_ + t0 + tc];
    *(float4*)&xsf[m * XS + tc] = v;
  }
  __syncthreads();

  bf16x8 bfr[2][8];
#pragma unroll
  for (int tt = 0; tt < 2; ++tt) {
#pragma unroll
    for (int s = 0; s < 8; ++s) {
      float v0 = xsf[(s * 16 + lh8 + 0) * XS + tt * 32 + l31];
      float v1 = xsf[(s * 16 + lh8 + 1) * XS + tt * 32 + l31];
      float v2 = xsf[(s * 16 + lh8 + 2) * XS + tt * 32 + l31];
      float v3 = xsf[(s * 16 + lh8 + 3) * XS + tt * 32 + l31];
      float v4 = xsf[(s * 16 + lh8 + 4) * XS + tt * 32 + l31];
      float v5 = xsf[(s * 16 + lh8 + 5) * XS + tt * 32 + l31];
      float v6 = xsf[(s * 16 + lh8 + 6) * XS + tt * 32 + l31];
      float v7 = xsf[(s * 16 + lh8 + 7) * XS + tt * 32 + l31];
      u32x4 p = {pk2(v0, v1), pk2(v2, v3), pk2(v4, v5), pk2(v6, v7)};
      bfr[tt][s] = __builtin_bit_cast(bf16x8, p);
    }
  }
  __syncthreads();  // xsf dead -> obuf

  u16* obuf = (u16*)xsf;  // [64 t][258 o]
#pragma unroll
  for (int tt = 0; tt < 2; ++tt) {
#pragma unroll
    for (int i = 0; i < 2; ++i) {
      f32x16 acc;
#pragma unroll
      for (int r = 0; r < 16; ++r) acc[r] = 0.f;
#pragma unroll
      for (int s = 0; s < 8; ++s)
        acc = __builtin_amdgcn_mfma_f32_32x32x16_bf16(afr[i][s], bfr[tt][s], acc, 0, 0, 0);
      int ot = 2 * wv + i;
      int t = tt * 32 + l31;
      float sc = (ot < 4) ? 1.44269504f : 1.0f;  // scale q (o<128) by log2e
#pragma unroll
      for (int r = 0; r < 16; ++r) {
        int orow = (r & 3) + 8 * (r >> 2) + 4 * (lane >> 5);
        float v = acc[r] + cqk[ot * 32 + orow];
        v = v > 0.f ? v : 0.01f * v;
        obuf[t * 258 + ot * 32 + orow] = f2bf(v * sc);
      }
    }
  }
  __syncthreads();

  const u32* ob32 = (const u32*)obuf;
#pragma unroll
  for (int g = 0; g < 8; ++g) {
    int G = wv * 8 + g;
    int mat = G >> 4;
    int t = (G & 15) * 4 + (lane >> 4);
    int og2 = lane & 15;
    int wbase = t * 129 + mat * 64 + og2 * 4;
    u32x4 vv = {ob32[wbase], ob32[wbase + 1], ob32[wbase + 2], ob32[wbase + 3]};
    u32* dst = (u32*)((mat ? kT : qT) + ((size_t)(b * T_ + t0 + t)) * 128) + og2 * 4;
    *(u32x4*)dst = vv;
  }
}

// ---------------------------------------------------------------------------
// attn v11 (resubmit; R5 bench was a container-infra failure, kernel audited
// clean): 4 waves/SIMD WITHOUT work duplication (v10 proved occupancy helps
// but its mh-split doubled S+softmax work). 1024 thr = 16 waves =
// qt(4) x ks(4: 32-k slice of a 128-k tile). Per wave: 8 unique S-MFMA,
// softmax for own 32 k's, 8 PV-MFMA (own 32 k x all 128 m) -> per-tile
// MFMA totals identical to v8 (128 S + 128 PV) at double the occupancy.
// Epilogue: 4-way k-partial combine in two LDS rounds (contiguous b128,
// conflict-free), then the o-MLP on 16 waves. Staging: 2 K + 2 V vecs
// per thread (same bytes as v8). VGPR budget ~128 (4 waves/SIMD cap).
#define QSTR 136  // u16: 68 words == 4 mod 32 (conflict-free)
#define VSTR 136
#define KTILE 128
#define NKT  (T_ / KTILE)
#define CINIT 0.52876637f   // log2(log2 e)

__global__ __launch_bounds__(1024) void attn_mfma_kernel(
    const u16* __restrict__ qT, const u16* __restrict__ kT,
    const u16* __restrict__ vB, const u16* __restrict__ Ao_bf,
    const float* __restrict__ co, const float* __restrict__ Aofp,
    const float* __restrict__ meanv, float* __restrict__ out) {
  extern __shared__ u16 smem[];
  // loop (u16 offsets): ks dbuf [128][QSTR] x2, vs dbuf [128][VSTR] x2
  u16* ks0 = smem;                 // bytes [0, 34816)
  u16* ks1 = smem + 17408;         // bytes [34816, 69632)
  u16* vs0 = smem + 34816;         // bytes [69632, 104448)
  u16* vs1 = smem + 52224;         // bytes [104448, 139264)
  // epilogue aliases (loop buffers dead after E1):
  float* pbuf  = (float*)smem;             // round A: 32 slots x 4KB = 128 KB
  u16*   ptbuf = smem + 32768;             // bytes [65536, 100352): P^T bf16
  float* dls   = (float*)(smem + 69632);   // bytes [139264, 141312): den[4][128]

  int b = blockIdx.y;
  int q0 = blockIdx.x * 128;
  int tid = threadIdx.x;
  int lane = tid & 63;
  int wv = tid >> 6;                 // 0..15
  int l31 = lane & 31;
  int h = lane >> 5;
  int lh8 = h * 8;
  int qt = wv & 3;                   // q-tile (32 q's)
  int ks = wv >> 2;                  // 32-k slice of the 128-k tile

  const u16* gkb = kT + (size_t)b * T_ * 128;
  const u16* gvb = vB + (size_t)b * M_ * T_;
  int sr = tid >> 3;                 // staging row 0..127
  int sc = (tid & 7) * 16;           // staging col (u16) 0..112

  // persistent Q B-frags straight from global (one-time, L2-resident)
  bf16x8 qfrag[8];
  {
    const u16* qrow = qT + (size_t)(b * T_ + q0 + qt * 32 + l31) * 128 + lh8;
#pragma unroll
    for (int s = 0; s < 8; ++s) qfrag[s] = ldfrag(qrow + s * 16);
  }

  u32x4 kreg[2], vreg[2];
  kreg[0] = *(const u32x4*)&gkb[(size_t)sr * 128 + sc];
  kreg[1] = *(const u32x4*)&gkb[(size_t)sr * 128 + sc + 8];
  vreg[0] = *(const u32x4*)&gvb[(size_t)sr * T_ + sc];
  vreg[1] = *(const u32x4*)&gvb[(size_t)sr * T_ + sc + 8];
  *(u32x4*)&ks0[sr * QSTR + sc] = kreg[0];
  *(u32x4*)&ks0[sr * QSTR + sc + 8] = kreg[1];
  *(u32x4*)&vs0[sr * VSTR + sc] = vreg[0];
  *(u32x4*)&vs0[sr * VSTR + sc + 8] = vreg[1];
  kreg[0] = *(const u32x4*)&gkb[(size_t)(KTILE + sr) * 128 + sc];
  kreg[1] = *(const u32x4*)&gkb[(size_t)(KTILE + sr) * 128 + sc + 8];
  vreg[0] = *(const u32x4*)&gvb[(size_t)sr * T_ + KTILE + sc];
  vreg[1] = *(const u32x4*)&gvb[(size_t)sr * T_ + KTILE + sc + 8];

  f32x16 pacc[4];
  float den = 0.f;
#pragma unroll
  for (int i = 0; i < 16; ++i) {
    pacc[0][i] = 0.f; pacc[1][i] = 0.f; pacc[2][i] = 0.f; pacc[3][i] = 0.f;
  }

  for (int kt = 0; kt < NKT; ++kt) {
    u16* kcur = (kt & 1) ? ks1 : ks0;
    u16* knxt = (kt & 1) ? ks0 : ks1;
    u16* vcur = (kt & 1) ? vs1 : vs0;
    u16* vnxt = (kt & 1) ? vs0 : vs1;
    __syncthreads();  // staging(kt) visible; prev readers of nxt drained

    // stage tile kt+1; prefetch tile kt+2
    if (kt < NKT - 1) {
      *(u32x4*)&knxt[sr * QSTR + sc] = kreg[0];
      *(u32x4*)&knxt[sr * QSTR + sc + 8] = kreg[1];
      *(u32x4*)&vnxt[sr * VSTR + sc] = vreg[0];
      *(u32x4*)&vnxt[sr * VSTR + sc + 8] = vreg[1];
      int kn = (kt + 2 < NKT) ? (kt + 2) * KTILE : (NKT - 1) * KTILE;
      kreg[0] = *(const u32x4*)&gkb[(size_t)(kn + sr) * 128 + sc];
      kreg[1] = *(const u32x4*)&gkb[(size_t)(kn + sr) * 128 + sc + 8];
      vreg[0] = *(const u32x4*)&gvb[(size_t)sr * T_ + kn + sc];
      vreg[1] = *(const u32x4*)&gvb[(size_t)sr * T_ + kn + sc + 8];
    }

    // S'[k][q] = mfma(K, Q) over this wave's 32 k's
    f32x16 sacc;
#pragma unroll
    for (int i = 0; i < 16; ++i) sacc[i] = CINIT;
    {
      const u16* krow = &kcur[(ks * 32 + l31) * QSTR + lh8];
#pragma unroll
      for (int s = 0; s < 8; ++s) {
        bf16x8 kf = ldfrag(krow + s * 16);
        sacc = __builtin_amdgcn_mfma_f32_32x32x16_bf16(kf, qfrag[s], sacc, 0, 0, 0);
      }
    }

    // diagonal adjust (scaled domain): x -> x*d + C*(1-d)
    if (kt * KTILE + ks * 32 == q0 + qt * 32) {
#pragma unroll
      for (int r = 0; r < 16; ++r) {
        int row = (r & 3) + 8 * (r >> 2) + 4 * h;
        if (row == l31) sacc[r] = fmaf(sacc[r], 0.97790291f, 0.01168420f);
      }
    }

    // w = exp2(exp2(s')) == exp(exp(qk)); den; pack + half-wave exchange
    float w[16];
#pragma unroll
    for (int r = 0; r < 16; ++r) w[r] = ex2(ex2(sacc[r]));
    {
      float d0 = (w[0] + w[1]) + (w[2] + w[3]);
      float d1 = (w[4] + w[5]) + (w[6] + w[7]);
      float d2 = (w[8] + w[9]) + (w[10] + w[11]);
      float d3 = (w[12] + w[13]) + (w[14] + w[15]);
      den += (d0 + d1) + (d2 + d3);
    }
    u32 p00 = pk2(w[0], w[1]),  p01 = pk2(w[2], w[3]);
    u32 p10 = pk2(w[4], w[5]),  p11 = pk2(w[6], w[7]);
    u32 p20 = pk2(w[8], w[9]),  p21 = pk2(w[10], w[11]);
    u32 p30 = pk2(w[12], w[13]), p31 = pk2(w[14], w[15]);
    u32 e0 = __shfl_xor(h ? p00 : p10, 32, 64);
    u32 e1 = __shfl_xor(h ? p01 : p11, 32, 64);
    u32 e2 = __shfl_xor(h ? p20 : p30, 32, 64);
    u32 e3 = __shfl_xor(h ? p21 : p31, 32, 64);
    u32x4 f0 = h ? u32x4{e0, e1, p10, p11} : u32x4{p00, p01, e0, e1};
    u32x4 f1 = h ? u32x4{e2, e3, p30, p31} : u32x4{p20, p21, e2, e3};
    bf16x8 bw0 = __builtin_bit_cast(bf16x8, f0);
    bf16x8 bw1 = __builtin_bit_cast(bf16x8, f1);

    // PV partials: this wave's 32 k's, all 128 m
#pragma unroll
    for (int mt = 0; mt < 4; ++mt) {
      const u16* vrow = &vcur[(mt * 32 + l31) * VSTR + ks * 32 + lh8];
      bf16x8 vf0 = ldfrag(vrow);
      bf16x8 vf1 = ldfrag(vrow + 16);
      pacc[mt] = __builtin_amdgcn_mfma_f32_32x32x16_bf16(vf0, bw0, pacc[mt], 0, 0, 0);
      pacc[mt] = __builtin_amdgcn_mfma_f32_32x32x16_bf16(vf1, bw1, pacc[mt], 0, 0, 0);
    }
  }

  // per-q denominator for this wave's 32-k slice (both h halves summed)
  float dq = den + __shfl_xor(den, 32, 64);

  __syncthreads();  // [E1] all loop reads done -> aliases safe

  // round A: ks 1,3 publish partials; ks 1,2,3 publish den
  if (ks != 0 && lane < 32) dls[ks * 128 + qt * 32 + l31] = dq;
  if (ks & 1) {
    int sidx = ks >> 1;
#pragma unroll
    for (int mt = 0; mt < 4; ++mt) {
      float* pb = &pbuf[(((sidx * 4 + qt) * 4 + mt) << 10)];
#pragma unroll
      for (int g = 0; g < 4; ++g) {
        f32x4 v = {pacc[mt][4 * g], pacc[mt][4 * g + 1],
                   pacc[mt][4 * g + 2], pacc[mt][4 * g + 3]};
        *(f32x4*)(pb + (g << 8) + lane * 4) = v;
      }
    }
  }
  __syncthreads();  // [E2]

  if (!(ks & 1)) {  // ks 0,2 absorb
    int sidx = ks >> 1;
#pragma unroll
    for (int mt = 0; mt < 4; ++mt) {
      const float* pb = &pbuf[(((sidx * 4 + qt) * 4 + mt) << 10)];
#pragma unroll
      for (int g = 0; g < 4; ++g) {
        f32x4 t = *(const f32x4*)(pb + (g << 8) + lane * 4);
        pacc[mt][4 * g]     += t[0];
        pacc[mt][4 * g + 1] += t[1];
        pacc[mt][4 * g + 2] += t[2];
        pacc[mt][4 * g + 3] += t[3];
      }
    }
  }
  __syncthreads();  // [E3]

  // round B: ks 2 publishes its (2+3) sum
  if (ks == 2) {
#pragma unroll
    for (int mt = 0; mt < 4; ++mt) {
      float* pb = &pbuf[((qt * 4 + mt) << 10)];
#pragma unroll
      for (int g = 0; g < 4; ++g) {
        f32x4 v = {pacc[mt][4 * g], pacc[mt][4 * g + 1],
                   pacc[mt][4 * g + 2], pacc[mt][4 * g + 3]};
        *(f32x4*)(pb + (g << 8) + lane * 4) = v;
      }
    }
  }
  __syncthreads();  // [E4]

  if (ks == 0) {  // final sum, normalize, write P^T bf16
    float dtot = dq + dls[128 + qt * 32 + l31] + dls[256 + qt * 32 + l31]
               + dls[384 + qt * 32 + l31];
    float rden = 1.f / dtot;
#pragma unroll
    for (int mt = 0; mt < 4; ++mt) {
      const float* pb = &pbuf[((qt * 4 + mt) << 10)];
#pragma unroll
      for (int g = 0; g < 4; ++g) {
        f32x4 t = *(const f32x4*)(pb + (g << 8) + lane * 4);
        float v0 = (pacc[mt][4 * g + 0] + t[0]) * rden;
        float v1 = (pacc[mt][4 * g + 1] + t[1]) * rden;
        float v2 = (pacc[mt][4 * g + 2] + t[2]) * rden;
        float v3 = (pacc[mt][4 * g + 3] + t[3]) * rden;
        int m0 = mt * 32 + 8 * g + 4 * h;
        u32x2 wp = {pk2(v0, v1), pk2(v2, v3)};
        *(u32x2*)&ptbuf[(qt * 32 + l31) * QSTR + m0] = wp;
      }
    }
  }
  __syncthreads();  // [E5] P^T visible

  // o-MLP epilogue: 16 waves = o-tile (wv&3) x q-tile (wv>>2), 8 MFMA each
  bf16x8 aofr[8];
  {
    const u16* ap = Ao_bf + ((wv & 3) * 32 + l31) * 128 + lh8;
#pragma unroll
    for (int s = 0; s < 8; ++s) aofr[s] = ldfrag(ap + 16 * s);
  }
  {
    int qt2 = wv >> 2;
    bf16x8 pfr[8];
    const u16* pp = &ptbuf[(qt2 * 32 + l31) * QSTR + lh8];
#pragma unroll
    for (int s = 0; s < 8; ++s) pfr[s] = ldfrag(pp + 16 * s);
    f32x16 oacc;
#pragma unroll
    for (int r = 0; r < 16; ++r) oacc[r] = 0.f;
#pragma unroll
    for (int s = 0; s < 8; ++s)
      oacc = __builtin_amdgcn_mfma_f32_32x32x16_bf16(aofr[s], pfr[s], oacc, 0, 0, 0);
#pragma unroll
    for (int r = 0; r < 16; ++r) {
      int orow = (wv & 3) * 32 + (r & 3) + 8 * (r >> 2) + 4 * h;
      float v = oacc[r] + co[orow];
      v = v > 0.f ? v : 0.01f * v;
      out[((size_t)(b * M_ + orow)) * TOUT_ + q0 + qt2 * 32 + l31] = v;
    }
  }

  // rep_ex tail
  if (blockIdx.x == 0 && tid < 128) {
    float acc = co[tid];
    const float* mv = meanv + b * 128;
    for (int m = 0; m < 128; ++m) acc = fmaf(Aofp[tid * 128 + m], mv[m], acc);
    acc = acc > 0.f ? acc : 0.01f * acc;
    out[((size_t)(b * M_ + tid)) * TOUT_ + 2048] = acc;
  }
}

// ---------------------------------------------------------------------------
extern "C" void kernel_launch(void* const* d_in, const int* in_sizes, int n_in,
                              void* d_out, int out_size, void* d_ws, size_t ws_size,
                              hipStream_t stream) {
  (void)in_sizes; (void)n_in; (void)out_size; (void)ws_size;
  const float* pattern = (const float*)d_in[0];
  const float* value   = (const float*)d_in[1];
  const float* Wq1 = (const float*)d_in[3];
  const float* bq1 = (const float*)d_in[4];
  const float* Wq2 = (const float*)d_in[5];
  const float* bq2 = (const float*)d_in[6];
  const float* Wk1 = (const float*)d_in[7];
  const float* bk1 = (const float*)d_in[8];
  const float* Wk2 = (const float*)d_in[9];
  const float* bk2 = (const float*)d_in[10];
  const float* Wo1 = (const float*)d_in[11];
  const float* bo1 = (const float*)d_in[12];
  const float* Wo2 = (const float*)d_in[13];
  const float* bo2 = (const float*)d_in[14];

  float* ws     = (float*)d_ws;
  float* A      = ws + A_OFF;
  float* c      = ws + C_OFF;
  float* meanv  = ws + MEAN_OFF;
  u16*   Aqk_bf = (u16*)(ws + AQKBF_OFF);
  u16*   Ao_bf  = (u16*)(ws + AOBF_OFF);
  u16*   qT     = (u16*)(ws + QT_OFF);
  u16*   kT     = (u16*)(ws + KT_OFF);
  u16*   vB     = (u16*)(ws + VB_OFF);
  float* out    = (float*)d_out;

  fuse_weights_all<<<384, 128, 0, stream>>>(
      Wq1, bq1, Wq2, bq2, Wk1, bk1, Wk2, bk2, Wo1, bo1, Wo2, bo2,
      A, c, Aqk_bf, Ao_bf);

  prep_kernel<<<512 + B_ * M_, 256, 0, stream>>>(
      pattern, Aqk_bf, c, qT, kT, value, vB, meanv);

  // LDS: loop 139,264 B (ks/vs dbuf) + dls 2,048 B = 141,312 B (1 block/CU)
  size_t lds_bytes = 141312;
  attn_mfma_kernel<<<dim3(T_ / 128, B_), 1024, lds_bytes, stream>>>(
      qT, kT, vB, Ao_bf, c + 256, A, meanv, out);
}

// Round 7
// 195.289 us; speedup vs baseline: 1.2906x; 1.2906x over previous
//
#include <hip/hip_runtime.h>
#include <hip/hip_bf16.h>
#include <math.h>

#define B_    16
#define M_    128
#define T_    2048
#define H_    512
#define TOUT_ 2049

typedef unsigned short u16;
typedef unsigned int   u32;
typedef __bf16 bf16x8 __attribute__((ext_vector_type(8)));
typedef float  f32x16 __attribute__((ext_vector_type(16)));
typedef float  f32x4  __attribute__((ext_vector_type(4)));
typedef u32    u32x4  __attribute__((ext_vector_type(4)));
typedef u32    u32x2  __attribute__((ext_vector_type(2)));

// ws layout (float units):
#define A_OFF     0                       // fp32 Ao only [128][128]
#define C_OFF     16384                   // c[3][128]
#define MEAN_OFF  16896                   // meanv [2048]
#define AQKBF_OFF 19200                   // u16 [256][128] = 16384 fl
#define AOBF_OFF  35584                   // u16 [128][128] = 8192 fl
#define QT_OFF    43776
#define KT_OFF    (43776 + 2097152)
#define VB_OFF    (43776 + 2 * 2097152)

static __device__ __forceinline__ u16 f2bf(float f) {
  u32 u = __float_as_uint(f);
  u = (u + 0x7FFFu + ((u >> 16) & 1u)) >> 16;
  return (u16)u;
}
static __device__ __forceinline__ u32 pk2(float lo, float hi) {
  __hip_bfloat162 h = __float22bfloat162_rn(float2{lo, hi});
  u32 r;
  __builtin_memcpy(&r, &h, 4);
  return r;
}
static __device__ __forceinline__ bf16x8 ldfrag(const u16* p) {
  return __builtin_bit_cast(bf16x8, *(const u32x4*)p);
}
static __device__ __forceinline__ float ex2(float x) {
#if __has_builtin(__builtin_amdgcn_exp2f)
  return __builtin_amdgcn_exp2f(x);  // v_exp_f32 = 2^x
#else
  return exp2f(x);
#endif
}

// ---------------------------------------------------------------------------
__global__ __launch_bounds__(128) void fuse_weights_all(
    const float* __restrict__ W1q, const float* __restrict__ b1q,
    const float* __restrict__ W2q, const float* __restrict__ b2q,
    const float* __restrict__ W1k, const float* __restrict__ b1k,
    const float* __restrict__ W2k, const float* __restrict__ b2k,
    const float* __restrict__ W1o, const float* __restrict__ b1o,
    const float* __restrict__ W2o, const float* __restrict__ b2o,
    float* __restrict__ A, float* __restrict__ c,
    u16* __restrict__ Aqk_bf, u16* __restrict__ Ao_bf) {
  __shared__ float w2row[H_];
  int which = blockIdx.x >> 7;
  int o = blockIdx.x & 127;
  const float* W1 = which == 0 ? W1q : which == 1 ? W1k : W1o;
  const float* b1 = which == 0 ? b1q : which == 1 ? b1k : b1o;
  const float* W2 = which == 0 ? W2q : which == 1 ? W2k : W2o;
  const float* b2 = which == 0 ? b2q : which == 1 ? b2k : b2o;
  int m = threadIdx.x;
  for (int h = m; h < H_; h += 128) w2row[h] = W2[o * H_ + h];
  __syncthreads();
  float acc = 0.f;
#pragma unroll 8
  for (int h = 0; h < H_; ++h) acc = fmaf(w2row[h], W1[h * M_ + m], acc);
  u16 ab = f2bf(acc);
  if (which == 0)      Aqk_bf[o * 128 + m] = ab;
  else if (which == 1) Aqk_bf[(128 + o) * 128 + m] = ab;
  else               { Ao_bf[o * 128 + m] = ab; A[o * M_ + m] = acc; }
  if (m < 64) {
    float cc = 0.f;
    for (int h = m; h < H_; h += 64) cc = fmaf(w2row[h], b1[h], cc);
#pragma unroll
    for (int off = 32; off > 0; off >>= 1) cc += __shfl_down(cc, off, 64);
    if (m == 0) c[which * 128 + o] = cc + b2[o];
  }
}

// ---------------------------------------------------------------------------
// prep: blocks [0,512) = q/k MLP (MFMA, coalesced I/O);
//       blocks [512,2560) = value cast + windowed mean
// q outputs (o<128) pre-scaled by log2(e): exp(exp(qk)) =
// exp2(exp2(qk*log2e + log2(log2e))).
#define XS 68

__global__ __launch_bounds__(256) void prep_kernel(
    const float* __restrict__ pattern, const u16* __restrict__ Aqk_bf,
    const float* __restrict__ cqk, u16* __restrict__ qT, u16* __restrict__ kT,
    const float* __restrict__ value, u16* __restrict__ vb,
    float* __restrict__ meanv) {
  __shared__ alignas(16) float xsf[128 * XS];
  int bx = blockIdx.x;
  int tid = threadIdx.x;

  if (bx >= 512) {
    int bm = bx - 512;
    float* red = xsf;
    const float* row = value + (size_t)bm * T_;
    int i0 = tid * 8;
    float4 a = *(const float4*)(row + i0);
    float4 bq = *(const float4*)(row + i0 + 4);
    u32x4 o = {pk2(a.x, a.y), pk2(a.z, a.w), pk2(bq.x, bq.y), pk2(bq.z, bq.w)};
    *(u32x4*)&vb[(size_t)bm * T_ + i0] = o;
    float vals[8] = {a.x, a.y, a.z, a.w, bq.x, bq.y, bq.z, bq.w};
    float s = 0.f;
#pragma unroll
    for (int j = 0; j < 8; ++j) {
      int idx = i0 + j;
      if (idx >= 33 && idx < T_ - 1) s += vals[j];
    }
    red[tid] = s;
    __syncthreads();
    for (int st = 128; st > 0; st >>= 1) {
      if (tid < st) red[tid] += red[tid + st];
      __syncthreads();
    }
    if (tid == 0) meanv[bm] = red[0] * (1.f / 2014.f);
    return;
  }

  int b = bx >> 5;
  int t0 = (bx & 31) * 64;
  int lane = tid & 63;
  int wv = tid >> 6;
  int l31 = lane & 31;
  int lh8 = (lane >> 5) * 8;

  bf16x8 afr[2][8];
#pragma unroll
  for (int i = 0; i < 2; ++i) {
    const u16* ap = Aqk_bf + ((2 * wv + i) * 32 + l31) * 128 + lh8;
#pragma unroll
    for (int s = 0; s < 8; ++s) afr[i][s] = ldfrag(ap + 16 * s);
  }

#pragma unroll
  for (int rep = 0; rep < 8; ++rep) {
    int m = rep * 16 + (tid >> 4);
    int tc = (tid & 15) * 4;
    float4 v = *(const float4*)&pattern[(size_t)(b * M_ + m) * T_ + t0 + tc];
    *(float4*)&xsf[m * XS + tc] = v;
  }
  __syncthreads();

  bf16x8 bfr[2][8];
#pragma unroll
  for (int tt = 0; tt < 2; ++tt) {
#pragma unroll
    for (int s = 0; s < 8; ++s) {
      float v0 = xsf[(s * 16 + lh8 + 0) * XS + tt * 32 + l31];
      float v1 = xsf[(s * 16 + lh8 + 1) * XS + tt * 32 + l31];
      float v2 = xsf[(s * 16 + lh8 + 2) * XS + tt * 32 + l31];
      float v3 = xsf[(s * 16 + lh8 + 3) * XS + tt * 32 + l31];
      float v4 = xsf[(s * 16 + lh8 + 4) * XS + tt * 32 + l31];
      float v5 = xsf[(s * 16 + lh8 + 5) * XS + tt * 32 + l31];
      float v6 = xsf[(s * 16 + lh8 + 6) * XS + tt * 32 + l31];
      float v7 = xsf[(s * 16 + lh8 + 7) * XS + tt * 32 + l31];
      u32x4 p = {pk2(v0, v1), pk2(v2, v3), pk2(v4, v5), pk2(v6, v7)};
      bfr[tt][s] = __builtin_bit_cast(bf16x8, p);
    }
  }
  __syncthreads();  // xsf dead -> obuf

  u16* obuf = (u16*)xsf;  // [64 t][258 o]
#pragma unroll
  for (int tt = 0; tt < 2; ++tt) {
#pragma unroll
    for (int i = 0; i < 2; ++i) {
      f32x16 acc;
#pragma unroll
      for (int r = 0; r < 16; ++r) acc[r] = 0.f;
#pragma unroll
      for (int s = 0; s < 8; ++s)
        acc = __builtin_amdgcn_mfma_f32_32x32x16_bf16(afr[i][s], bfr[tt][s], acc, 0, 0, 0);
      int ot = 2 * wv + i;
      int t = tt * 32 + l31;
      float sc = (ot < 4) ? 1.44269504f : 1.0f;  // scale q (o<128) by log2e
#pragma unroll
      for (int r = 0; r < 16; ++r) {
        int orow = (r & 3) + 8 * (r >> 2) + 4 * (lane >> 5);
        float v = acc[r] + cqk[ot * 32 + orow];
        v = v > 0.f ? v : 0.01f * v;
        obuf[t * 258 + ot * 32 + orow] = f2bf(v * sc);
      }
    }
  }
  __syncthreads();

  const u32* ob32 = (const u32*)obuf;
#pragma unroll
  for (int g = 0; g < 8; ++g) {
    int G = wv * 8 + g;
    int mat = G >> 4;
    int t = (G & 15) * 4 + (lane >> 4);
    int og2 = lane & 15;
    int wbase = t * 129 + mat * 64 + og2 * 4;
    u32x4 vv = {ob32[wbase], ob32[wbase + 1], ob32[wbase + 2], ob32[wbase + 3]};
    u32* dst = (u32*)((mat ? kT : qT) + ((size_t)(b * T_ + t0 + t)) * 128) + og2 * 4;
    *(u32x4*)dst = vv;
  }
}

// ---------------------------------------------------------------------------
// attn v12: within-tile producer/consumer at 4 waves/SIMD, spill-free.
// v11's pacc[4] (64 VGPR) forced spills (FETCH 70->272 MB). Fix: P goes
// through LDS once per tile so each (mt,qt) output is fully k-reduced in
// ONE wave -> pacc = f32x16 (the 16-reg minimum). 1024 thr = 16 waves:
//   waves 0-7  (qt=wv&3, ksl=wv>>2): 8 S-MFMA -> softmax -> write P[q][k]
//   waves 8-15: stage K/V(kt+1) (global latency hides under S phase)
//   barrier; ALL 16 waves (mt=wv>>2, qt=wv&3): 4 PV-MFMA from V,P in LDS.
// KTILE=64, K/V dbuf + single P buffer = 90 KB LDS. No shfl exchange, no
// epilogue partial-combine. __launch_bounds__(1024,4) -> 128 VGPR cap,
// est. peak ~85.
#define QSTR 136  // u16: 68 words == 4 mod 32 (conflict-free)
#define VSTR 72   // u16: 36 words == 4 mod 32
#define PSTR 72
#define PTSTR 136
#define KTILE 64
#define NKT  (T_ / KTILE)
#define CINIT 0.52876637f   // log2(log2 e)

__global__ __launch_bounds__(1024, 4) void attn_mfma_kernel(
    const u16* __restrict__ qT, const u16* __restrict__ kT,
    const u16* __restrict__ vB, const u16* __restrict__ Ao_bf,
    const float* __restrict__ co, const float* __restrict__ Aofp,
    const float* __restrict__ meanv, float* __restrict__ out) {
  extern __shared__ u16 smem[];
  // u16 offsets:
  u16* ks0 = smem;                 // [64][QSTR]   bytes [0, 17408)
  u16* ks1 = smem + 8704;          //              bytes [17408, 34816)
  u16* vs0 = smem + 17408;         // [128][VSTR]  bytes [34816, 53248)
  u16* vs1 = smem + 26624;         //              bytes [53248, 71680)
  u16* pls = smem + 35840;         // [128][PSTR]  bytes [71680, 90112)
  // epilogue aliases:
  float* dls   = (float*)smem;     // [2][128] f32, dead-K region
  u16*   ptbuf = smem + 17408;     // [128][PTSTR] 34816 B, dead-V region

  int b = blockIdx.y;
  int q0 = blockIdx.x * 128;
  int tid = threadIdx.x;
  int lane = tid & 63;
  int wv = tid >> 6;                 // 0..15
  int l31 = lane & 31;
  int h = lane >> 5;
  int lh8 = h * 8;
  int qt = wv & 3;                   // q-tile (32 q's) -- S role AND PV role
  int ksl = wv >> 2;                 // S role: 32-k slice (waves 0-7: 0..1)
  int mt = wv >> 2;                  // PV role: m-tile 0..3

  const u16* gkb = kT + (size_t)b * T_ * 128;
  const u16* gvb = vB + (size_t)b * M_ * T_;

  // persistent Q B-frags (S-waves only), straight from global (L2-resident)
  bf16x8 qfrag[8];
  if (wv < 8) {
    const u16* qrow = qT + (size_t)(b * T_ + q0 + qt * 32 + l31) * 128 + lh8;
#pragma unroll
    for (int s = 0; s < 8; ++s) qfrag[s] = ldfrag(qrow + s * 16);
  }

  // prologue: all 1024 threads stage tile 0 (1 K-vec + 1 V-vec each)
  {
    int kr = tid >> 4, kc = (tid & 15) * 8;   // K [64][128]: 1024 vecs
    int vr = tid >> 3, vc = (tid & 7) * 8;    // V [128][64]: 1024 vecs
    *(u32x4*)&ks0[kr * QSTR + kc] = *(const u32x4*)&gkb[(size_t)kr * 128 + kc];
    *(u32x4*)&vs0[vr * VSTR + vc] = *(const u32x4*)&gvb[(size_t)vr * T_ + vc];
  }

  f32x16 pacc;
  float den = 0.f;
#pragma unroll
  for (int i = 0; i < 16; ++i) pacc[i] = 0.f;

  int t9 = tid & 511;  // staging-thread index for waves 8-15

  for (int kt = 0; kt < NKT; ++kt) {
    u16* kcur = (kt & 1) ? ks1 : ks0;
    u16* knxt = (kt & 1) ? ks0 : ks1;
    u16* vcur = (kt & 1) ? vs1 : vs0;
    u16* vnxt = (kt & 1) ? vs0 : vs1;
    __syncthreads();  // [A] staging(kt) + P-consumed(kt-1) visible

    u32x4 kr0, kr1, vr0, vr1;
    if (wv < 8) {
      // ---- producer: S + softmax + P-write ----
      f32x16 sacc;
#pragma unroll
      for (int i = 0; i < 16; ++i) sacc[i] = CINIT;
      {
        const u16* krow = &kcur[(ksl * 32 + l31) * QSTR + lh8];
#pragma unroll
        for (int s = 0; s < 8; ++s) {
          bf16x8 kf = ldfrag(krow + s * 16);
          sacc = __builtin_amdgcn_mfma_f32_32x32x16_bf16(kf, qfrag[s], sacc, 0, 0, 0);
        }
      }
      // diagonal adjust (scaled domain): x -> x*d + C*(1-d)
      if (kt * KTILE + ksl * 32 == q0 + qt * 32) {
#pragma unroll
        for (int r = 0; r < 16; ++r) {
          int row = (r & 3) + 8 * (r >> 2) + 4 * h;
          if (row == l31) sacc[r] = fmaf(sacc[r], 0.97790291f, 0.01168420f);
        }
      }
      // w = exp2(exp2(s')) == exp(exp(qk)); accumulate den; write P[q][k]
      float w[16];
#pragma unroll
      for (int r = 0; r < 16; ++r) w[r] = ex2(ex2(sacc[r]));
      {
        float d0 = (w[0] + w[1]) + (w[2] + w[3]);
        float d1 = (w[4] + w[5]) + (w[6] + w[7]);
        float d2 = (w[8] + w[9]) + (w[10] + w[11]);
        float d3 = (w[12] + w[13]) + (w[14] + w[15]);
        den += (d0 + d1) + (d2 + d3);
      }
      u16* prow = &pls[(qt * 32 + l31) * PSTR + ksl * 32 + 4 * h];
#pragma unroll
      for (int g = 0; g < 4; ++g) {
        u32x2 wp = {pk2(w[4 * g], w[4 * g + 1]), pk2(w[4 * g + 2], w[4 * g + 3])};
        *(u32x2*)&prow[8 * g] = wp;
      }
    } else if (kt < NKT - 1) {
      // ---- stager: issue global loads of tile kt+1 (latency hides under S)
      int kn = (kt + 1) * KTILE;
      int ka0 = t9 >> 4, kb0 = (t9 & 15) * 8;
      int va0 = t9 >> 3, vb0 = (t9 & 7) * 8;
      kr0 = *(const u32x4*)&gkb[(size_t)(kn + ka0) * 128 + kb0];
      kr1 = *(const u32x4*)&gkb[(size_t)(kn + ka0 + 32) * 128 + kb0];
      vr0 = *(const u32x4*)&gvb[(size_t)va0 * T_ + kn + vb0];
      vr1 = *(const u32x4*)&gvb[(size_t)(va0 + 64) * T_ + kn + vb0];
    }

    __syncthreads();  // [B] P(kt) ready

    // ---- all 16 waves: PV for (mt, qt), 4 MFMA over the 64-k tile ----
    {
      const u16* vrow = &vcur[(mt * 32 + l31) * VSTR + lh8];
      const u16* prow = &pls[(qt * 32 + l31) * PSTR + lh8];
#pragma unroll
      for (int k16 = 0; k16 < 4; ++k16) {
        bf16x8 vf = ldfrag(vrow + k16 * 16);
        bf16x8 pf = ldfrag(prow + k16 * 16);
        pacc = __builtin_amdgcn_mfma_f32_32x32x16_bf16(vf, pf, pacc, 0, 0, 0);
      }
    }

    // ---- stager: write tile kt+1 into nxt (before next barrier A) ----
    if (wv >= 8 && kt < NKT - 1) {
      int ka0 = t9 >> 4, kb0 = (t9 & 15) * 8;
      int va0 = t9 >> 3, vb0 = (t9 & 7) * 8;
      *(u32x4*)&knxt[ka0 * QSTR + kb0] = kr0;
      *(u32x4*)&knxt[(ka0 + 32) * QSTR + kb0] = kr1;
      *(u32x4*)&vnxt[va0 * VSTR + vb0] = vr0;
      *(u32x4*)&vnxt[(va0 + 64) * VSTR + vb0] = vr1;
    }
  }

  __syncthreads();  // [E0] all loop reads done -> aliases safe
  float dq = den + __shfl_xor(den, 32, 64);
  if (wv < 8 && lane < 32) dls[ksl * 128 + qt * 32 + l31] = dq;
  __syncthreads();  // [E1] dls visible

  // normalize + write attn^T [q][m] (each wave owns its (mt,qt) chunk)
  {
    float rden = 1.f / (dls[qt * 32 + l31] + dls[128 + qt * 32 + l31]);
    u16* pt = &ptbuf[(qt * 32 + l31) * PTSTR + mt * 32 + 4 * h];
#pragma unroll
    for (int g = 0; g < 4; ++g) {
      u32x2 wp = {pk2(pacc[4 * g] * rden, pacc[4 * g + 1] * rden),
                  pk2(pacc[4 * g + 2] * rden, pacc[4 * g + 3] * rden)};
      *(u32x2*)&pt[8 * g] = wp;
    }
  }
  __syncthreads();  // [E2] attn^T visible

  // o-MLP epilogue: 16 waves = o-tile (wv&3) x q-tile (wv>>2), 8 MFMA each
  bf16x8 aofr[8];
  {
    const u16* ap = Ao_bf + ((wv & 3) * 32 + l31) * 128 + lh8;
#pragma unroll
    for (int s = 0; s < 8; ++s) aofr[s] = ldfrag(ap + 16 * s);
  }
  {
    int qt2 = wv >> 2;
    bf16x8 pfr[8];
    const u16* pp = &ptbuf[(qt2 * 32 + l31) * PTSTR + lh8];
#pragma unroll
    for (int s = 0; s < 8; ++s) pfr[s] = ldfrag(pp + 16 * s);
    f32x16 oacc;
#pragma unroll
    for (int r = 0; r < 16; ++r) oacc[r] = 0.f;
#pragma unroll
    for (int s = 0; s < 8; ++s)
      oacc = __builtin_amdgcn_mfma_f32_32x32x16_bf16(aofr[s], pfr[s], oacc, 0, 0, 0);
#pragma unroll
    for (int r = 0; r < 16; ++r) {
      int orow = (wv & 3) * 32 + (r & 3) + 8 * (r >> 2) + 4 * h;
      float v = oacc[r] + co[orow];
      v = v > 0.f ? v : 0.01f * v;
      out[((size_t)(b * M_ + orow)) * TOUT_ + q0 + qt2 * 32 + l31] = v;
    }
  }

  // rep_ex tail
  if (blockIdx.x == 0 && tid < 128) {
    float acc = co[tid];
    const float* mv = meanv + b * 128;
    for (int m = 0; m < 128; ++m) acc = fmaf(Aofp[tid * 128 + m], mv[m], acc);
    acc = acc > 0.f ? acc : 0.01f * acc;
    out[((size_t)(b * M_ + tid)) * TOUT_ + 2048] = acc;
  }
}

// ---------------------------------------------------------------------------
extern "C" void kernel_launch(void* const* d_in, const int* in_sizes, int n_in,
                              void* d_out, int out_size, void* d_ws, size_t ws_size,
                              hipStream_t stream) {
  (void)in_sizes; (void)n_in; (void)out_size; (void)ws_size;
  const float* pattern = (const float*)d_in[0];
  const float* value   = (const float*)d_in[1];
  const float* Wq1 = (const float*)d_in[3];
  const float* bq1 = (const float*)d_in[4];
  const float* Wq2 = (const float*)d_in[5];
  const float* bq2 = (const float*)d_in[6];
  const float* Wk1 = (const float*)d_in[7];
  const float* bk1 = (const float*)d_in[8];
  const float* Wk2 = (const float*)d_in[9];
  const float* bk2 = (const float*)d_in[10];
  const float* Wo1 = (const float*)d_in[11];
  const float* bo1 = (const float*)d_in[12];
  const float* Wo2 = (const float*)d_in[13];
  const float* bo2 = (const float*)d_in[14];

  float* ws     = (float*)d_ws;
  float* A      = ws + A_OFF;
  float* c      = ws + C_OFF;
  float* meanv  = ws + MEAN_OFF;
  u16*   Aqk_bf = (u16*)(ws + AQKBF_OFF);
  u16*   Ao_bf  = (u16*)(ws + AOBF_OFF);
  u16*   qT     = (u16*)(ws + QT_OFF);
  u16*   kT     = (u16*)(ws + KT_OFF);
  u16*   vB     = (u16*)(ws + VB_OFF);
  float* out    = (float*)d_out;

  fuse_weights_all<<<384, 128, 0, stream>>>(
      Wq1, bq1, Wq2, bq2, Wk1, bk1, Wk2, bk2, Wo1, bo1, Wo2, bo2,
      A, c, Aqk_bf, Ao_bf);

  prep_kernel<<<512 + B_ * M_, 256, 0, stream>>>(
      pattern, Aqk_bf, c, qT, kT, value, vB, meanv);

  // LDS: ks dbuf 34,816 + vs dbuf 36,864 + P 18,432 = 90,112 B (1 block/CU)
  size_t lds_bytes = 90112;
  attn_mfma_kernel<<<dim3(T_ / 128, B_), 1024, lds_bytes, stream>>>(
      qT, kT, vB, Ao_bf, c + 256, A, meanv, out);
}

// Round 8
// 189.192 us; speedup vs baseline: 1.3322x; 1.0322x over previous
//
#include <hip/hip_runtime.h>
#include <hip/hip_bf16.h>
#include <math.h>

#define B_    16
#define M_    128
#define T_    2048
#define H_    512
#define TOUT_ 2049

typedef unsigned short u16;
typedef unsigned int   u32;
typedef __bf16 bf16x8 __attribute__((ext_vector_type(8)));
typedef float  f32x16 __attribute__((ext_vector_type(16)));
typedef float  f32x4  __attribute__((ext_vector_type(4)));
typedef u32    u32x4  __attribute__((ext_vector_type(4)));
typedef u32    u32x2  __attribute__((ext_vector_type(2)));

// ws layout (float units):
#define A_OFF     0                       // fp32 Ao only [128][128]
#define C_OFF     16384                   // c[3][128]
#define MEAN_OFF  16896                   // meanv [2048]
#define AQKBF_OFF 19200                   // u16 [256][128] = 16384 fl
#define AOBF_OFF  35584                   // u16 [128][128] = 8192 fl
#define QT_OFF    43776
#define KT_OFF    (43776 + 2097152)
#define VB_OFF    (43776 + 2 * 2097152)

static __device__ __forceinline__ u16 f2bf(float f) {
  u32 u = __float_as_uint(f);
  u = (u + 0x7FFFu + ((u >> 16) & 1u)) >> 16;
  return (u16)u;
}
static __device__ __forceinline__ u32 pk2(float lo, float hi) {
  __hip_bfloat162 h = __float22bfloat162_rn(float2{lo, hi});
  u32 r;
  __builtin_memcpy(&r, &h, 4);
  return r;
}
static __device__ __forceinline__ bf16x8 ldfrag(const u16* p) {
  return __builtin_bit_cast(bf16x8, *(const u32x4*)p);
}
static __device__ __forceinline__ float ex2(float x) {
#if __has_builtin(__builtin_amdgcn_exp2f)
  return __builtin_amdgcn_exp2f(x);  // v_exp_f32 = 2^x
#else
  return exp2f(x);
#endif
}

// ---------------------------------------------------------------------------
// fuse: blocks [0,384) = weight fusion; blocks [384, 384+2048) = value cast
// + windowed mean (moved here from prep: independent of fuse outputs, so it
// overlaps with the weight blocks instead of serializing inside prep).
__global__ __launch_bounds__(128) void fuse_weights_all(
    const float* __restrict__ W1q, const float* __restrict__ b1q,
    const float* __restrict__ W2q, const float* __restrict__ b2q,
    const float* __restrict__ W1k, const float* __restrict__ b1k,
    const float* __restrict__ W2k, const float* __restrict__ b2k,
    const float* __restrict__ W1o, const float* __restrict__ b1o,
    const float* __restrict__ W2o, const float* __restrict__ b2o,
    float* __restrict__ A, float* __restrict__ c,
    u16* __restrict__ Aqk_bf, u16* __restrict__ Ao_bf,
    const float* __restrict__ value, u16* __restrict__ vb,
    float* __restrict__ meanv) {
  __shared__ float w2row[H_];
  int tid = threadIdx.x;

  if (blockIdx.x >= 384) {
    int bm = blockIdx.x - 384;
    float* red = w2row;
    const float* row = value + (size_t)bm * T_;
    int i0 = tid * 16;
    float4 a0 = *(const float4*)(row + i0);
    float4 a1 = *(const float4*)(row + i0 + 4);
    float4 a2 = *(const float4*)(row + i0 + 8);
    float4 a3 = *(const float4*)(row + i0 + 12);
    u32x4 o0 = {pk2(a0.x, a0.y), pk2(a0.z, a0.w), pk2(a1.x, a1.y), pk2(a1.z, a1.w)};
    u32x4 o1 = {pk2(a2.x, a2.y), pk2(a2.z, a2.w), pk2(a3.x, a3.y), pk2(a3.z, a3.w)};
    *(u32x4*)&vb[(size_t)bm * T_ + i0] = o0;
    *(u32x4*)&vb[(size_t)bm * T_ + i0 + 8] = o1;
    float vals[16] = {a0.x, a0.y, a0.z, a0.w, a1.x, a1.y, a1.z, a1.w,
                      a2.x, a2.y, a2.z, a2.w, a3.x, a3.y, a3.z, a3.w};
    float s = 0.f;
#pragma unroll
    for (int j = 0; j < 16; ++j) {
      int idx = i0 + j;
      if (idx >= 33 && idx < T_ - 1) s += vals[j];
    }
    red[tid] = s;
    __syncthreads();
    for (int st = 64; st > 0; st >>= 1) {
      if (tid < st) red[tid] += red[tid + st];
      __syncthreads();
    }
    if (tid == 0) meanv[bm] = red[0] * (1.f / 2014.f);
    return;
  }

  int which = blockIdx.x >> 7;
  int o = blockIdx.x & 127;
  const float* W1 = which == 0 ? W1q : which == 1 ? W1k : W1o;
  const float* b1 = which == 0 ? b1q : which == 1 ? b1k : b1o;
  const float* W2 = which == 0 ? W2q : which == 1 ? W2k : W2o;
  const float* b2 = which == 0 ? b2q : which == 1 ? b2k : b2o;
  int m = tid;
  for (int h = m; h < H_; h += 128) w2row[h] = W2[o * H_ + h];
  __syncthreads();
  float acc = 0.f;
#pragma unroll 8
  for (int h = 0; h < H_; ++h) acc = fmaf(w2row[h], W1[h * M_ + m], acc);
  u16 ab = f2bf(acc);
  if (which == 0)      Aqk_bf[o * 128 + m] = ab;
  else if (which == 1) Aqk_bf[(128 + o) * 128 + m] = ab;
  else               { Ao_bf[o * 128 + m] = ab; A[o * M_ + m] = acc; }
  if (m < 64) {
    float cc = 0.f;
    for (int h = m; h < H_; h += 64) cc = fmaf(w2row[h], b1[h], cc);
#pragma unroll
    for (int off = 32; off > 0; off >>= 1) cc += __shfl_down(cc, off, 64);
    if (m == 0) c[which * 128 + o] = cc + b2[o];
  }
}

// ---------------------------------------------------------------------------
// prep: 512 blocks, q/k MLP only (value part moved to fuse launch).
// q outputs (o<128) pre-scaled by log2(e): exp(exp(qk)) =
// exp2(exp2(qk*log2e + log2(log2e))).
#define XS 68

__global__ __launch_bounds__(256) void prep_kernel(
    const float* __restrict__ pattern, const u16* __restrict__ Aqk_bf,
    const float* __restrict__ cqk, u16* __restrict__ qT, u16* __restrict__ kT) {
  __shared__ alignas(16) float xsf[128 * XS];
  int bx = blockIdx.x;
  int tid = threadIdx.x;

  int b = bx >> 5;
  int t0 = (bx & 31) * 64;
  int lane = tid & 63;
  int wv = tid >> 6;
  int l31 = lane & 31;
  int lh8 = (lane >> 5) * 8;

  bf16x8 afr[2][8];
#pragma unroll
  for (int i = 0; i < 2; ++i) {
    const u16* ap = Aqk_bf + ((2 * wv + i) * 32 + l31) * 128 + lh8;
#pragma unroll
    for (int s = 0; s < 8; ++s) afr[i][s] = ldfrag(ap + 16 * s);
  }

#pragma unroll
  for (int rep = 0; rep < 8; ++rep) {
    int m = rep * 16 + (tid >> 4);
    int tc = (tid & 15) * 4;
    float4 v = *(const float4*)&pattern[(size_t)(b * M_ + m) * T_ + t0 + tc];
    *(float4*)&xsf[m * XS + tc] = v;
  }
  __syncthreads();

  bf16x8 bfr[2][8];
#pragma unroll
  for (int tt = 0; tt < 2; ++tt) {
#pragma unroll
    for (int s = 0; s < 8; ++s) {
      float v0 = xsf[(s * 16 + lh8 + 0) * XS + tt * 32 + l31];
      float v1 = xsf[(s * 16 + lh8 + 1) * XS + tt * 32 + l31];
      float v2 = xsf[(s * 16 + lh8 + 2) * XS + tt * 32 + l31];
      float v3 = xsf[(s * 16 + lh8 + 3) * XS + tt * 32 + l31];
      float v4 = xsf[(s * 16 + lh8 + 4) * XS + tt * 32 + l31];
      float v5 = xsf[(s * 16 + lh8 + 5) * XS + tt * 32 + l31];
      float v6 = xsf[(s * 16 + lh8 + 6) * XS + tt * 32 + l31];
      float v7 = xsf[(s * 16 + lh8 + 7) * XS + tt * 32 + l31];
      u32x4 p = {pk2(v0, v1), pk2(v2, v3), pk2(v4, v5), pk2(v6, v7)};
      bfr[tt][s] = __builtin_bit_cast(bf16x8, p);
    }
  }
  __syncthreads();  // xsf dead -> obuf

  u16* obuf = (u16*)xsf;  // [64 t][258 o]
#pragma unroll
  for (int tt = 0; tt < 2; ++tt) {
#pragma unroll
    for (int i = 0; i < 2; ++i) {
      f32x16 acc;
#pragma unroll
      for (int r = 0; r < 16; ++r) acc[r] = 0.f;
#pragma unroll
      for (int s = 0; s < 8; ++s)
        acc = __builtin_amdgcn_mfma_f32_32x32x16_bf16(afr[i][s], bfr[tt][s], acc, 0, 0, 0);
      int ot = 2 * wv + i;
      int t = tt * 32 + l31;
      float sc = (ot < 4) ? 1.44269504f : 1.0f;  // scale q (o<128) by log2e
#pragma unroll
      for (int r = 0; r < 16; ++r) {
        int orow = (r & 3) + 8 * (r >> 2) + 4 * (lane >> 5);
        float v = acc[r] + cqk[ot * 32 + orow];
        v = v > 0.f ? v : 0.01f * v;
        obuf[t * 258 + ot * 32 + orow] = f2bf(v * sc);
      }
    }
  }
  __syncthreads();

  const u32* ob32 = (const u32*)obuf;
#pragma unroll
  for (int g = 0; g < 8; ++g) {
    int G = wv * 8 + g;
    int mat = G >> 4;
    int t = (G & 15) * 4 + (lane >> 4);
    int og2 = lane & 15;
    int wbase = t * 129 + mat * 64 + og2 * 4;
    u32x4 vv = {ob32[wbase], ob32[wbase + 1], ob32[wbase + 2], ob32[wbase + 3]};
    u32* dst = (u32*)((mat ? kT : qT) + ((size_t)(b * T_ + t0 + t)) * 128) + og2 * 4;
    *(u32x4*)dst = vv;
  }
}

// ---------------------------------------------------------------------------
// attn v13: producer/consumer WAVE SPECIALIZATION with cross-tile pipeline.
// Four prior schedules (2w lockstep, 2w ILP, 4w phase-split) all hit the
// same ~4650 cyc/64-k wall: every one phase-serializes S+softmax vs PV at a
// barrier. v13 runs them CONCURRENTLY on different waves & tiles:
//   waves 0-7  (qt x ksl): S(i) -> softmax -> P-write, every iteration
//   waves 8-15 (mt x qh):  PV(i-1) for 2 (mt,qt) pairs + K/V stage + prefetch
// One barrier/iter. P dbuf, K dbuf, V tri-buf (tiles i-1, i, i+1 live).
// KTILE=64, NKT=32. LDS 128,000 B. __launch_bounds__(1024,4) -> 128 VGPR cap.
#define QSTR 136  // u16: 68 words == 4 mod 32 (conflict-free)
#define VSTR 72   // u16: 36 words == 4 mod 32
#define PSTR 72
#define PTSTR 136
#define KTILE 64
#define NKT  (T_ / KTILE)
#define CINIT 0.52876637f   // log2(log2 e)

__global__ __launch_bounds__(1024, 4) void attn_mfma_kernel(
    const u16* __restrict__ qT, const u16* __restrict__ kT,
    const u16* __restrict__ vB, const u16* __restrict__ Ao_bf,
    const float* __restrict__ co, const float* __restrict__ Aofp,
    const float* __restrict__ meanv, float* __restrict__ out) {
  extern __shared__ u16 smem[];
  // u16 offsets (bytes = 2x):
  u16* kb0 = smem;                  // [64][QSTR]   bytes [0, 17408)
  u16* kb1 = smem + 8704;           //              bytes [17408, 34816)
  u16* vbf0 = smem + 17408;         // [128][VSTR]  bytes [34816, 53248)
  u16* vbf1 = smem + 26624;         //              bytes [53248, 71680)
  u16* vbf2 = smem + 35840;         //              bytes [71680, 90112)
  u16* pb0 = smem + 45056;          // [128][PSTR]  bytes [90112, 108544)
  u16* pb1 = smem + 54272;          //              bytes [108544, 126976)
  float* dls = (float*)(smem + 63488);  // [2][128]  bytes [126976, 128000)
  u16* ptbuf = smem;                // epilogue alias [0, 34816) (K dead)

  int b = blockIdx.y;
  int q0 = blockIdx.x * 128;
  int tid = threadIdx.x;
  int lane = tid & 63;
  int wv = tid >> 6;                 // 0..15
  int l31 = lane & 31;
  int h = lane >> 5;
  int lh8 = h * 8;
  bool prod = wv < 8;
  int qt = wv & 3;                   // producer q-tile
  int ksl = (wv >> 2) & 1;           // producer 32-k slice
  int cw = wv & 7;                   // consumer index (wv-8 for consumers)
  int mt = cw & 3;                   // consumer m-tile
  int qh = cw >> 2;                  // consumer q-pair (qt = 2*qh, 2*qh+1)

  const u16* gkb = kT + (size_t)b * T_ * 128;
  const u16* gvb = vB + (size_t)b * M_ * T_;

  // producer: persistent Q B-frags from global (L2-resident)
  bf16x8 qfrag[8];
  if (prod) {
    const u16* qrow = qT + (size_t)(b * T_ + q0 + qt * 32 + l31) * 128 + lh8;
#pragma unroll
    for (int s = 0; s < 8; ++s) qfrag[s] = ldfrag(qrow + s * 16);
  }

  // prologue: all 1024 threads stage tile 0
  {
    int kr = tid >> 4, kc = (tid & 15) * 8;
    int vr = tid >> 3, vc = (tid & 7) * 8;
    *(u32x4*)&kb0[kr * QSTR + kc] = *(const u32x4*)&gkb[(size_t)kr * 128 + kc];
    *(u32x4*)&vbf0[vr * VSTR + vc] = *(const u32x4*)&gvb[(size_t)vr * T_ + vc];
  }

  // consumer: prefetch tile 1 into regs (2 K-vecs + 2 V-vecs)
  int ct = tid & 511;
  int kr0 = ct >> 4, kc0 = (ct & 15) * 8;
  int vr0 = ct >> 3, vc0 = (ct & 7) * 8;
  u32x4 kreg0, kreg1, vreg0, vreg1;
  if (!prod) {
    kreg0 = *(const u32x4*)&gkb[(size_t)(KTILE + kr0) * 128 + kc0];
    kreg1 = *(const u32x4*)&gkb[(size_t)(KTILE + kr0 + 32) * 128 + kc0];
    vreg0 = *(const u32x4*)&gvb[(size_t)vr0 * T_ + KTILE + vc0];
    vreg1 = *(const u32x4*)&gvb[(size_t)(vr0 + 64) * T_ + KTILE + vc0];
  }

  f32x16 pacc0, pacc1;
  float den = 0.f;
#pragma unroll
  for (int i = 0; i < 16; ++i) { pacc0[i] = 0.f; pacc1[i] = 0.f; }

  u16* vprev = vbf2;  // (i-1)%3
  u16* vcur  = vbf0;  // i%3
  u16* vnxt  = vbf1;  // (i+1)%3

  __syncthreads();  // tile 0 staged

  for (int i = 0; i <= NKT; ++i) {
    if (prod) {
      if (i < NKT) {
        // ---- producer: S(i) + softmax + P-write ----
        u16* kcur = (i & 1) ? kb1 : kb0;
        f32x16 sacc;
#pragma unroll
        for (int r = 0; r < 16; ++r) sacc[r] = CINIT;
        {
          const u16* krow = &kcur[(ksl * 32 + l31) * QSTR + lh8];
#pragma unroll
          for (int s = 0; s < 8; ++s) {
            bf16x8 kf = ldfrag(krow + s * 16);
            sacc = __builtin_amdgcn_mfma_f32_32x32x16_bf16(kf, qfrag[s], sacc, 0, 0, 0);
          }
        }
        if (i * KTILE + ksl * 32 == q0 + qt * 32) {
#pragma unroll
          for (int r = 0; r < 16; ++r) {
            int row = (r & 3) + 8 * (r >> 2) + 4 * h;
            if (row == l31) sacc[r] = fmaf(sacc[r], 0.97790291f, 0.01168420f);
          }
        }
        float w[16];
#pragma unroll
        for (int r = 0; r < 16; ++r) w[r] = ex2(ex2(sacc[r]));
        {
          float d0 = (w[0] + w[1]) + (w[2] + w[3]);
          float d1 = (w[4] + w[5]) + (w[6] + w[7]);
          float d2 = (w[8] + w[9]) + (w[10] + w[11]);
          float d3 = (w[12] + w[13]) + (w[14] + w[15]);
          den += (d0 + d1) + (d2 + d3);
        }
        u16* pw = (i & 1) ? pb1 : pb0;
        u16* prow = &pw[(qt * 32 + l31) * PSTR + ksl * 32 + 4 * h];
#pragma unroll
        for (int g = 0; g < 4; ++g) {
          u32x2 wp = {pk2(w[4 * g], w[4 * g + 1]), pk2(w[4 * g + 2], w[4 * g + 3])};
          *(u32x2*)&prow[8 * g] = wp;
        }
      }
    } else {
      // ---- consumer: stage(i+1) writes, PV(i-1), prefetch(i+2) ----
      if (i + 1 < NKT) {
        u16* kw = ((i + 1) & 1) ? kb1 : kb0;
        *(u32x4*)&kw[kr0 * QSTR + kc0] = kreg0;
        *(u32x4*)&kw[(kr0 + 32) * QSTR + kc0] = kreg1;
        *(u32x4*)&vnxt[vr0 * VSTR + vc0] = vreg0;
        *(u32x4*)&vnxt[(vr0 + 64) * VSTR + vc0] = vreg1;
      }
      if (i >= 1) {
        const u16* pr = ((i - 1) & 1) ? pb1 : pb0;
        const u16* vrow = &vprev[(mt * 32 + l31) * VSTR + lh8];
        const u16* prow0 = &pr[((qh * 2) * 32 + l31) * PSTR + lh8];
        const u16* prow1 = &pr[((qh * 2 + 1) * 32 + l31) * PSTR + lh8];
#pragma unroll
        for (int k16 = 0; k16 < 4; ++k16) {
          bf16x8 vf = ldfrag(vrow + k16 * 16);
          bf16x8 pf0 = ldfrag(prow0 + k16 * 16);
          bf16x8 pf1 = ldfrag(prow1 + k16 * 16);
          pacc0 = __builtin_amdgcn_mfma_f32_32x32x16_bf16(vf, pf0, pacc0, 0, 0, 0);
          pacc1 = __builtin_amdgcn_mfma_f32_32x32x16_bf16(vf, pf1, pacc1, 0, 0, 0);
        }
      }
      if (i + 2 < NKT) {
        int kn2 = (i + 2) * KTILE;
        kreg0 = *(const u32x4*)&gkb[(size_t)(kn2 + kr0) * 128 + kc0];
        kreg1 = *(const u32x4*)&gkb[(size_t)(kn2 + kr0 + 32) * 128 + kc0];
        vreg0 = *(const u32x4*)&gvb[(size_t)vr0 * T_ + kn2 + vc0];
        vreg1 = *(const u32x4*)&gvb[(size_t)(vr0 + 64) * T_ + kn2 + vc0];
      }
    }
    u16* tmp = vprev; vprev = vcur; vcur = vnxt; vnxt = tmp;
    __syncthreads();
  }

  // epilogue: producers publish den; consumers normalize + write attn^T
  if (prod) {
    float dq = den + __shfl_xor(den, 32, 64);
    if (lane < 32) dls[ksl * 128 + qt * 32 + l31] = dq;
  }
  __syncthreads();  // [E1] dls visible; kbuf dead -> ptbuf alias safe

  if (!prod) {
#pragma unroll
    for (int j = 0; j < 2; ++j) {
      int qt2 = qh * 2 + j;
      float rden = 1.f / (dls[qt2 * 32 + l31] + dls[128 + qt2 * 32 + l31]);
      const f32x16& pa = j ? pacc1 : pacc0;
      u16* pt = &ptbuf[(qt2 * 32 + l31) * PTSTR + mt * 32 + 4 * h];
#pragma unroll
      for (int g = 0; g < 4; ++g) {
        u32x2 wp = {pk2(pa[4 * g] * rden, pa[4 * g + 1] * rden),
                    pk2(pa[4 * g + 2] * rden, pa[4 * g + 3] * rden)};
        *(u32x2*)&pt[8 * g] = wp;
      }
    }
  }
  __syncthreads();  // [E2] attn^T visible

  // o-MLP epilogue: 16 waves = o-tile (wv&3) x q-tile (wv>>2), 8 MFMA each
  bf16x8 aofr[8];
  {
    const u16* ap = Ao_bf + ((wv & 3) * 32 + l31) * 128 + lh8;
#pragma unroll
    for (int s = 0; s < 8; ++s) aofr[s] = ldfrag(ap + 16 * s);
  }
  {
    int qt2 = wv >> 2;
    bf16x8 pfr[8];
    const u16* pp = &ptbuf[(qt2 * 32 + l31) * PTSTR + lh8];
#pragma unroll
    for (int s = 0; s < 8; ++s) pfr[s] = ldfrag(pp + 16 * s);
    f32x16 oacc;
#pragma unroll
    for (int r = 0; r < 16; ++r) oacc[r] = 0.f;
#pragma unroll
    for (int s = 0; s < 8; ++s)
      oacc = __builtin_amdgcn_mfma_f32_32x32x16_bf16(aofr[s], pfr[s], oacc, 0, 0, 0);
#pragma unroll
    for (int r = 0; r < 16; ++r) {
      int orow = (wv & 3) * 32 + (r & 3) + 8 * (r >> 2) + 4 * h;
      float v = oacc[r] + co[orow];
      v = v > 0.f ? v : 0.01f * v;
      out[((size_t)(b * M_ + orow)) * TOUT_ + q0 + qt2 * 32 + l31] = v;
    }
  }

  // rep_ex tail
  if (blockIdx.x == 0 && tid < 128) {
    float acc = co[tid];
    const float* mv = meanv + b * 128;
    for (int m = 0; m < 128; ++m) acc = fmaf(Aofp[tid * 128 + m], mv[m], acc);
    acc = acc > 0.f ? acc : 0.01f * acc;
    out[((size_t)(b * M_ + tid)) * TOUT_ + 2048] = acc;
  }
}

// ---------------------------------------------------------------------------
extern "C" void kernel_launch(void* const* d_in, const int* in_sizes, int n_in,
                              void* d_out, int out_size, void* d_ws, size_t ws_size,
                              hipStream_t stream) {
  (void)in_sizes; (void)n_in; (void)out_size; (void)ws_size;
  const float* pattern = (const float*)d_in[0];
  const float* value   = (const float*)d_in[1];
  const float* Wq1 = (const float*)d_in[3];
  const float* bq1 = (const float*)d_in[4];
  const float* Wq2 = (const float*)d_in[5];
  const float* bq2 = (const float*)d_in[6];
  const float* Wk1 = (const float*)d_in[7];
  const float* bk1 = (const float*)d_in[8];
  const float* Wk2 = (const float*)d_in[9];
  const float* bk2 = (const float*)d_in[10];
  const float* Wo1 = (const float*)d_in[11];
  const float* bo1 = (const float*)d_in[12];
  const float* Wo2 = (const float*)d_in[13];
  const float* bo2 = (const float*)d_in[14];

  float* ws     = (float*)d_ws;
  float* A      = ws + A_OFF;
  float* c      = ws + C_OFF;
  float* meanv  = ws + MEAN_OFF;
  u16*   Aqk_bf = (u16*)(ws + AQKBF_OFF);
  u16*   Ao_bf  = (u16*)(ws + AOBF_OFF);
  u16*   qT     = (u16*)(ws + QT_OFF);
  u16*   kT     = (u16*)(ws + KT_OFF);
  u16*   vB     = (u16*)(ws + VB_OFF);
  float* out    = (float*)d_out;

  fuse_weights_all<<<384 + B_ * M_, 128, 0, stream>>>(
      Wq1, bq1, Wq2, bq2, Wk1, bk1, Wk2, bk2, Wo1, bo1, Wo2, bo2,
      A, c, Aqk_bf, Ao_bf, value, vB, meanv);

  prep_kernel<<<512, 256, 0, stream>>>(pattern, Aqk_bf, c, qT, kT);

  // LDS: K dbuf 34,816 + V tri-buf 55,296 + P dbuf 36,864 + dls 1,024
  //    = 128,000 B -> 1 block/CU, 16 waves = 4 waves/SIMD
  size_t lds_bytes = 128000;
  attn_mfma_kernel<<<dim3(T_ / 128, B_), 1024, lds_bytes, stream>>>(
      qT, kT, vB, Ao_bf, c + 256, A, meanv, out);
}